// Round 5
// baseline (597.054 us; speedup 1.0000x reference)
//
#include <hip/hip_runtime.h>

// SparseGCNPredicator on MI355X — all float tensors are f32.
// R5: agg gathers 4 rows per load instruction (16-lane x uint4 subgroups,
// butterfly reduce); CSR build via wave-scan range allocation (no global
// prefix scan, no fill array); kernels fused -> 10 dispatches total.

typedef unsigned short ushort_t;
typedef unsigned int   uint_t;
typedef __attribute__((ext_vector_type(8))) short bf16x8;
typedef __attribute__((ext_vector_type(4))) float f32x4;

__device__ __forceinline__ float bf2f(uint_t u) { return __uint_as_float(u << 16); }
__device__ __forceinline__ ushort_t f2bf(float f) {
  uint_t x = __float_as_uint(f);
  x = x + 0x7fffu + ((x >> 16) & 1u);   // round-to-nearest-even
  return (ushort_t)(x >> 16);
}

// ---------------- CSR build ----------------

// deg histogram over dst + graph-count histogram over gidx, one kernel
__global__ __launch_bounds__(256) void k_degcnt(const int* __restrict__ dst, int* __restrict__ deg,
                                                const int* __restrict__ gidx, int* __restrict__ cnt,
                                                int E, int N) {
  int i = blockIdx.x * 256 + threadIdx.x;
  if (i < E) atomicAdd(&deg[dst[i]], 1);
  if (i < N) atomicAdd(&cnt[gidx[i]], 1);
}

// Ordering-free CSR range allocation: wave-scan of deg + one global atomic
// per wave. offs[i] = start of node i's range (becomes cursor for bucket).
// Also computes nrm. Replaces scanA/scanB/scanC/norm.
__global__ __launch_bounds__(256) void k_alloc(const int* __restrict__ deg, int* __restrict__ offs,
                                               float* __restrict__ nrm, int* __restrict__ gctr, int N) {
  int i = blockIdx.x * 256 + threadIdx.x;
  int lane = threadIdx.x & 63;
  int d = (i < N) ? deg[i] : 0;
  int incl = d;
#pragma unroll
  for (int sft = 1; sft < 64; sft <<= 1) {
    int nv = __shfl_up(incl, sft, 64);
    if (lane >= sft) incl += nv;
  }
  int wsum = __shfl(incl, 63, 64);
  int base = 0;
  if (lane == 63) base = atomicAdd(gctr, wsum);
  base = __shfl(base, 63, 64);
  if (i < N) {
    offs[i] = base + incl - d;             // start of range
    nrm[i] = (d > 0) ? rsqrtf((float)d) : 0.f;
  }
}

// bucket fill: offs is the live cursor; afterwards offs[i] == end of range
__global__ __launch_bounds__(256) void k_bucket(const int* __restrict__ src, const int* __restrict__ dst,
                                                int* __restrict__ offs, int* __restrict__ esrc, int E) {
  int e = blockIdx.x * 256 + threadIdx.x;
  if (e >= E) return;
  int d = dst[e];
  int p = atomicAdd(&offs[d], 1);
  esrc[p] = src[e];
}

// ---------------- W pre-transform (both weights in one kernel) ----------------
// Wf[(q*128 + n)*8 + j] = bf16(W[q*8+j][n])
__global__ __launch_bounds__(256) void k_prepW(const float* __restrict__ W1, ushort_t* __restrict__ Wf1,
                                               const float* __restrict__ W2, ushort_t* __restrict__ Wf2) {
  int b = blockIdx.x;
  const float* W = (b < 64) ? W1 : W2;
  ushort_t* Wf = (b < 64) ? Wf1 : Wf2;
  int idx = (b & 63) * 256 + threadIdx.x;     // 0..16383
  int n = idx & 127, k = idx >> 7;
  float v = W[(size_t)k * 128 + n];
  Wf[((size_t)(k >> 3) * 128 + n) * 8 + (k & 7)] = f2bf(v);
}

// ---------------- MFMA GEMM: Yb[r] = bf16( (X[r] @ W + b) * norm[r] ) ----------------
template <bool BF16IN>
__global__ __launch_bounds__(256) void k_gemm_mfma(const void* __restrict__ Xv, const ushort_t* __restrict__ Wf,
                                                   const float* __restrict__ bias, const float* __restrict__ nrm,
                                                   ushort_t* __restrict__ Yb, int nrows) {
  __shared__ ushort_t Xs[16384];   // [(q*128 + m)*8 + j]
  __shared__ ushort_t Ws[16384];   // [(q*128 + n)*8 + j]
  int tid = threadIdx.x;
  int r0 = blockIdx.x * 128;
  {
    const uint4* s = (const uint4*)Wf;
    uint4* d = (uint4*)Ws;
#pragma unroll
    for (int i = 0; i < 8; i++) d[tid + 256 * i] = s[tid + 256 * i];
  }
  if (BF16IN) {
    const uint4* Xp = (const uint4*)Xv;        // row = 16 uint4 (one chunk each)
    uint4* Xs4 = (uint4*)Xs;
#pragma unroll
    for (int i = 0; i < 8; i++) {
      int idx = tid + 256 * i;                 // 0..2047
      int m = idx >> 4, q = idx & 15;
      int gm = r0 + m;
      uint4 v = make_uint4(0u, 0u, 0u, 0u);
      if (gm < nrows) v = Xp[(size_t)gm * 16 + q];
      Xs4[q * 128 + m] = v;
    }
  } else {
    const float4* Xp = (const float4*)Xv;      // row = 32 float4
#pragma unroll
    for (int i = 0; i < 16; i++) {
      int idx = tid + 256 * i;                 // 0..4095
      int m = idx >> 5, k4 = idx & 31;
      int gm = r0 + m;
      float4 v = make_float4(0.f, 0.f, 0.f, 0.f);
      if (gm < nrows) v = Xp[(size_t)gm * 32 + k4];
      uint2 p;
      p.x = (uint_t)f2bf(v.x) | ((uint_t)f2bf(v.y) << 16);
      p.y = (uint_t)f2bf(v.z) | ((uint_t)f2bf(v.w) << 16);
      *((uint2*)(Xs + ((size_t)(k4 >> 1) * 128 + m) * 8 + (size_t)(k4 & 1) * 4)) = p;
    }
  }
  __syncthreads();

  int wave = tid >> 6, lane = tid & 63;
  int ln = lane & 15, quad = lane >> 4;
  const bf16x8* Xf = (const bf16x8*)Xs;
  const bf16x8* Wb = (const bf16x8*)Ws;
  f32x4 acc[2][8];
#pragma unroll
  for (int mt = 0; mt < 2; mt++)
#pragma unroll
    for (int ct = 0; ct < 8; ct++) acc[mt][ct] = (f32x4){0.f, 0.f, 0.f, 0.f};

#pragma unroll
  for (int kc = 0; kc < 4; kc++) {
    int q = kc * 4 + quad;
    bf16x8 a0 = Xf[q * 128 + wave * 32 + ln];
    bf16x8 a1 = Xf[q * 128 + wave * 32 + 16 + ln];
#pragma unroll
    for (int ct = 0; ct < 8; ct++) {
      bf16x8 b = Wb[q * 128 + ct * 16 + ln];
      acc[0][ct] = __builtin_amdgcn_mfma_f32_16x16x32_bf16(a0, b, acc[0][ct], 0, 0, 0);
      acc[1][ct] = __builtin_amdgcn_mfma_f32_16x16x32_bf16(a1, b, acc[1][ct], 0, 0, 0);
    }
  }

  // epilogue: D row = base_m + quad*4 + reg, col = ct*16 + ln
#pragma unroll
  for (int mt = 0; mt < 2; mt++) {
    int rbase = r0 + wave * 32 + mt * 16 + quad * 4;
    float nv[4];
#pragma unroll
    for (int reg = 0; reg < 4; reg++) {
      int r = rbase + reg;
      nv[reg] = (r < nrows) ? nrm[r] : 0.f;
    }
#pragma unroll
    for (int ct = 0; ct < 8; ct++) {
      int col = ct * 16 + ln;
      float bcol = bias[col];
#pragma unroll
      for (int reg = 0; reg < 4; reg++) {
        int r = rbase + reg;
        if (r < nrows) {
          float val = (acc[mt][ct][reg] + bcol) * nv[reg];
          Yb[(size_t)r * 128 + col] = f2bf(val);
        }
      }
    }
  }
}

// ---------------- Aggregation ----------------
// One wave per node. Lane = (sub, sl): sub = lane>>4 picks the edge within a
// group of 4, sl = lane&15 picks 8 channels (uint4 = 16 B). One load
// instruction gathers 4 rows. Main loop: 16 edges / 4 loads in flight.
// End: butterfly (xor 16, 32) combines the 4 subgroups.
__device__ __forceinline__ void acc8(float* a, uint4 g) {
  a[0] += __uint_as_float(g.x << 16); a[1] += __uint_as_float(g.x & 0xffff0000u);
  a[2] += __uint_as_float(g.y << 16); a[3] += __uint_as_float(g.y & 0xffff0000u);
  a[4] += __uint_as_float(g.z << 16); a[5] += __uint_as_float(g.z & 0xffff0000u);
  a[6] += __uint_as_float(g.w << 16); a[7] += __uint_as_float(g.w & 0xffff0000u);
}

template <bool POOL>
__global__ __launch_bounds__(256) void k_agg(const uint4* __restrict__ hn4, const int* __restrict__ endo,
                                             const int* __restrict__ deg, const float* __restrict__ nrm,
                                             const int* __restrict__ esrc, const int* __restrict__ gidx,
                                             uint4* __restrict__ outb, float* __restrict__ pool, int N) {
  int wave = threadIdx.x >> 6;
  int lane = threadIdx.x & 63;
  int i = blockIdx.x * 4 + wave;
  if (i >= N) return;
  int d = deg[i];
  int end = endo[i], e = end - d;
  int sub = lane >> 4, sl = lane & 15;
  float A[8] = {0.f, 0.f, 0.f, 0.f, 0.f, 0.f, 0.f, 0.f};
  float B[8] = {0.f, 0.f, 0.f, 0.f, 0.f, 0.f, 0.f, 0.f};
  float C[8] = {0.f, 0.f, 0.f, 0.f, 0.f, 0.f, 0.f, 0.f};
  float D[8] = {0.f, 0.f, 0.f, 0.f, 0.f, 0.f, 0.f, 0.f};
  for (; e + 16 <= end; e += 16) {
    int x0 = esrc[e + sub];
    int x1 = esrc[e + 4 + sub];
    int x2 = esrc[e + 8 + sub];
    int x3 = esrc[e + 12 + sub];
    uint4 g0 = hn4[(size_t)x0 * 16 + sl];
    uint4 g1 = hn4[(size_t)x1 * 16 + sl];
    uint4 g2 = hn4[(size_t)x2 * 16 + sl];
    uint4 g3 = hn4[(size_t)x3 * 16 + sl];
    acc8(A, g0); acc8(B, g1); acc8(C, g2); acc8(D, g3);
  }
  for (; e + 4 <= end; e += 4) {
    int x0 = esrc[e + sub];
    uint4 g0 = hn4[(size_t)x0 * 16 + sl];
    acc8(A, g0);
  }
  if (e < end) {
    int eIdx = e + sub;
    if (eIdx < end) {
      int x0 = esrc[eIdx];
      uint4 g0 = hn4[(size_t)x0 * 16 + sl];
      acc8(B, g0);
    }
  }
  float nv = nrm[i];
  float v[8];
#pragma unroll
  for (int k = 0; k < 8; k++) {
    float s = A[k] + B[k] + C[k] + D[k];
    s += __shfl_xor(s, 16, 64);
    s += __shfl_xor(s, 32, 64);
    v[k] = fmaxf(s * nv, 0.f);
  }
  if (POOL) {
    float p0, p1;
    if (sub == 0)      { p0 = v[0]; p1 = v[1]; }
    else if (sub == 1) { p0 = v[2]; p1 = v[3]; }
    else if (sub == 2) { p0 = v[4]; p1 = v[5]; }
    else               { p0 = v[6]; p1 = v[7]; }
    float* p = pool + (size_t)gidx[i] * 128 + sl * 8 + sub * 2;
    atomicAdd(p, p0);
    atomicAdd(p + 1, p1);
  } else if (sub == 0) {
    uint4 pk;
    pk.x = (uint_t)f2bf(v[0]) | ((uint_t)f2bf(v[1]) << 16);
    pk.y = (uint_t)f2bf(v[2]) | ((uint_t)f2bf(v[3]) << 16);
    pk.z = (uint_t)f2bf(v[4]) | ((uint_t)f2bf(v[5]) << 16);
    pk.w = (uint_t)f2bf(v[6]) | ((uint_t)f2bf(v[7]) << 16);
    outb[(size_t)i * 16 + sl] = pk;
  }
}

// ---------------- Head: mean -> FC(relu) -> dot(Wout) + bout ----------------
__global__ __launch_bounds__(128) void k_head(const float* __restrict__ pool, const int* __restrict__ cnt,
                                              const float* __restrict__ Wfc, const float* __restrict__ bfc,
                                              const float* __restrict__ Wout, const float* __restrict__ bout,
                                              float* __restrict__ out) {
  __shared__ float pv[128];
  __shared__ float red[128];
  int g = blockIdx.x, t = threadIdx.x;
  float c = fmaxf((float)cnt[g], 1.f);
  pv[t] = pool[(size_t)g * 128 + t] / c;
  __syncthreads();
  float acc = bfc[t];
#pragma unroll 8
  for (int k = 0; k < 128; k++) acc += pv[k] * Wfc[k * 128 + t];
  acc = fmaxf(acc, 0.f);
  red[t] = acc * Wout[t];
  __syncthreads();
  for (int o = 64; o > 0; o >>= 1) { if (t < o) red[t] += red[t + o]; __syncthreads(); }
  if (t == 0) out[g] = red[0] + bout[0];
}

// ---------------- launch ----------------

extern "C" void kernel_launch(void* const* d_in, const int* in_sizes, int n_in,
                              void* d_out, int out_size, void* d_ws, size_t ws_size,
                              hipStream_t stream) {
  const float* X    = (const float*)d_in[0];
  const int*   adj  = (const int*)d_in[1];
  const int*   gidx = (const int*)d_in[2];
  // d_in[3] = is_training (ignored; dropout rate is 0)
  const float* W1   = (const float*)d_in[4];
  const float* b1   = (const float*)d_in[5];
  const float* W2   = (const float*)d_in[6];
  const float* b2   = (const float*)d_in[7];
  const float* Wfc  = (const float*)d_in[8];
  const float* bfc  = (const float*)d_in[9];
  const float* Wout = (const float*)d_in[10];
  const float* bout = (const float*)d_in[11];
  (void)n_in; (void)ws_size;

  const int N = in_sizes[2];        // 100000
  const int E = in_sizes[1] / 2;    // 1600000
  const int G = out_size;           // 1024 (OUT=1)
  const int* srcv = adj;
  const int* dstv = adj + E;

  char* w = (char*)d_ws;
  size_t off = 0;
  auto alloc = [&](size_t bytes) -> void* {
    void* p = (void*)(w + off);
    off += (bytes + 255) & ~(size_t)255;
    return p;
  };
  // ---- zero-init region (ONE memset): deg | cnt | gctr | pool ----
  char* zbase = (char*)(w + off);
  int*   deg  = (int*)alloc((size_t)N * sizeof(int));
  int*   cnt  = (int*)alloc((size_t)G * sizeof(int));
  int*   gctr = (int*)alloc(256);
  float* pool = (float*)alloc((size_t)G * 128 * sizeof(float));
  size_t zbytes = (size_t)((char*)(w + off) - zbase);
  // ---- rest ----
  ushort_t* bufA = (ushort_t*)alloc((size_t)N * 128 * sizeof(ushort_t)); // hn bf16 (gemm out), both layers
  ushort_t* bufB = (ushort_t*)alloc((size_t)N * 128 * sizeof(ushort_t)); // layer-1 activations (bf16)
  float*    nrm  = (float*)alloc((size_t)N * sizeof(float));
  int*      offs = (int*)alloc((size_t)N * sizeof(int));                 // start, then live cursor -> end
  int*      esrc = (int*)alloc((size_t)E * sizeof(int));
  ushort_t* Wf1  = (ushort_t*)alloc((size_t)128 * 128 * sizeof(ushort_t));
  ushort_t* Wf2  = (ushort_t*)alloc((size_t)128 * 128 * sizeof(ushort_t));

  hipMemsetAsync(zbase, 0, zbytes, stream);

  k_prepW<<<128, 256, 0, stream>>>(W1, Wf1, W2, Wf2);
  k_degcnt<<<(E + 255) / 256, 256, 0, stream>>>(dstv, deg, gidx, cnt, E, N);
  k_alloc<<<(N + 255) / 256, 256, 0, stream>>>(deg, offs, nrm, gctr, N);
  k_bucket<<<(E + 255) / 256, 256, 0, stream>>>(srcv, dstv, offs, esrc, E);

  const int aggGrid = (N + 3) / 4;
  const int gemmGrid = (N + 127) / 128;
  // layer 1
  k_gemm_mfma<false><<<gemmGrid, 256, 0, stream>>>((const void*)X, Wf1, b1, nrm, bufA, N);
  k_agg<false><<<aggGrid, 256, 0, stream>>>((const uint4*)bufA, offs, deg, nrm, esrc, gidx,
                                            (uint4*)bufB, nullptr, N);
  // layer 2 (+ fused pooling)
  k_gemm_mfma<true><<<gemmGrid, 256, 0, stream>>>((const void*)bufB, Wf2, b2, nrm, bufA, N);
  k_agg<true><<<aggGrid, 256, 0, stream>>>((const uint4*)bufA, offs, deg, nrm, esrc, gidx,
                                           nullptr, pool, N);
  // head
  k_head<<<G, 128, 0, stream>>>(pool, cnt, Wfc, bfc, Wout, bout, (float*)d_out);
}